// Round 10
// baseline (312.021 us; speedup 1.0000x reference)
//
#include <hip/hip_runtime.h>
#include <hip/hip_bf16.h>
#include <cmath>

// TransformerBlock  B=4 T=2048 C=512 H=8 D=64  (f32 I/O, bf16 MFMA internal)

using u16 = unsigned short;
typedef __attribute__((ext_vector_type(4))) float f32x4;
typedef __attribute__((ext_vector_type(16))) float f32x16;
typedef __attribute__((ext_vector_type(8))) short bf16x8;

constexpr int B_ = 4, T_ = 2048, C_ = 512, H_ = 8, D_ = 64;
constexpr int BT = B_ * T_;                // 8192 rows
constexpr int KQV_SEC = B_ * H_ * T_ * D_; // 4194304 elems per k/q/v section

__device__ __forceinline__ float b2f(u16 u) {
    return __uint_as_float(((unsigned)u) << 16);
}
__device__ __forceinline__ u16 f2b(float f) {
    __hip_bfloat16 h = __float2bfloat16(f);
    return *reinterpret_cast<u16*>(&h);
}

// async global->LDS, 16B per lane; LDS dest = wave-uniform base + lane*16
__device__ __forceinline__ void gl_lds16(const u16* g, u16* l) {
    __builtin_amdgcn_global_load_lds(
        (const __attribute__((address_space(1))) unsigned int*)(const void*)g,
        (__attribute__((address_space(3))) unsigned int*)(void*)l, 16, 0, 0);
}

// ---------------- all weights f32 -> bf16, one launch ----------------
__global__ __launch_bounds__(256) void wcvt_all_k(const float* __restrict__ w0,
                                                  const float* __restrict__ w1,
                                                  const float* __restrict__ w2,
                                                  const float* __restrict__ w3,
                                                  u16* __restrict__ o0,
                                                  u16* __restrict__ o1,
                                                  u16* __restrict__ o2,
                                                  u16* __restrict__ o3) {
    const int i = blockIdx.x * 256 + threadIdx.x;
    const float* w; u16* o; int j;
    if (i < 196608) { w = w0; o = o0; j = i; }
    else if (i < 262144) { w = w1; o = o1; j = i - 196608; }
    else if (i < 393216) { w = w2; o = o2; j = i - 262144; }
    else { w = w3; o = o3; j = i - 393216; }
    float4 v = ((const float4*)w)[j];
    ushort4 u;
    u.x = f2b(v.x); u.y = f2b(v.y); u.z = f2b(v.z); u.w = f2b(v.w);
    ((ushort4*)o)[j] = u;
}

// ---------------- fused LayerNorm: f32 in -> bf16 normalized out ----------------
__global__ __launch_bounds__(256) void ln_fused_k(const float* __restrict__ x,
                                                  u16* __restrict__ o) {
    const int r = blockIdx.x;
    const int t = threadIdx.x;
    const float v0 = x[(size_t)r * C_ + t];
    const float v1 = x[(size_t)r * C_ + t + 256];
    __shared__ float rs[256], rq[256];
    rs[t] = v0 + v1;
    rq[t] = v0 * v0 + v1 * v1;
    __syncthreads();
    for (int k = 128; k; k >>= 1) {
        if (t < k) { rs[t] += rs[t + k]; rq[t] += rq[t + k]; }
        __syncthreads();
    }
    __shared__ float sm, sr;
    if (t == 0) {
        float m = rs[0] * (1.0f / C_);
        float var = rq[0] * (1.0f / C_) - m * m;
        sm = m;
        sr = rsqrtf(var + 1e-5f);
    }
    __syncthreads();
    const float m = sm, rstd = sr;
    o[(size_t)r * C_ + t] = f2b((v0 - m) * rstd);
    o[(size_t)r * C_ + t + 256] = f2b((v1 - m) * rstd);
}

// ---------------- MFMA GEMM: out = A(bf16 [M][K]) @ W(bf16 [N][K])^T ----------------
// 128x128 tile, BK=64, 4 waves each 64x64. global_load_lds staging with
// inverse-swizzled global source (rule #21).
// EPI: 0 kqv scatter (+bias, bf16; V section written TRANSPOSED [bh][d][T])
//      1 +bias+resid(f32)->f32 | 2 +bias,gelu->bf16 | 3 +resid->f32
template <int EPI>
__global__ __launch_bounds__(256) void gemm_mfma(const u16* __restrict__ A,
                                                 const u16* __restrict__ W,
                                                 const float* __restrict__ bias,
                                                 const float* __restrict__ resid,
                                                 void* __restrict__ out,
                                                 int K, int N) {
    __shared__ alignas(16) u16 Al[128 * 64];
    __shared__ alignas(16) u16 Bl[128 * 64];
    const int tid = threadIdx.x, lane = tid & 63, w = tid >> 6;
    const int g = lane >> 4, c = lane & 15;
    const int wm = w >> 1, wn = w & 1;
    const int n0 = blockIdx.x * 128, r0 = blockIdx.y * 128;

    const int l7 = lane & 7, l3 = lane >> 3;
    const int colHalf = ((l7 ^ l3) << 3);   // swizzled source column (elements)

    f32x4 acc[4][4] = {};
    const char* AlB = (const char*)Al;
    const char* BlB = (const char*)Bl;

    for (int kk = 0; kk < K; kk += 64) {
#pragma unroll
        for (int i = 0; i < 4; ++i) {
            const int s = w * 4 + i;
            const int row = s * 8 + l3;
            gl_lds16(A + (size_t)(r0 + row) * K + kk + colHalf, &Al[s * 512]);
            gl_lds16(W + (size_t)(n0 + row) * K + kk + colHalf, &Bl[s * 512]);
        }
        __syncthreads();

        bf16x8 af[4][2], bf[4][2];
#pragma unroll
        for (int mf = 0; mf < 4; ++mf) {
            const int ar = wm * 64 + mf * 16 + c;
#pragma unroll
            for (int ch = 0; ch < 2; ++ch)
                af[mf][ch] = *(const bf16x8*)(
                    AlB + ar * 128 + (((ch * 32 + g * 8) * 2) ^ ((ar & 7) << 4)));
        }
#pragma unroll
        for (int nf = 0; nf < 4; ++nf) {
            const int br = wn * 64 + nf * 16 + c;
#pragma unroll
            for (int ch = 0; ch < 2; ++ch)
                bf[nf][ch] = *(const bf16x8*)(
                    BlB + br * 128 + (((ch * 32 + g * 8) * 2) ^ ((br & 7) << 4)));
        }
#pragma unroll
        for (int mf = 0; mf < 4; ++mf)
#pragma unroll
            for (int nf = 0; nf < 4; ++nf)
#pragma unroll
                for (int ch = 0; ch < 2; ++ch)
                    acc[mf][nf] = __builtin_amdgcn_mfma_f32_16x16x32_bf16(
                        af[mf][ch], bf[nf][ch], acc[mf][nf], 0, 0, 0);
        __syncthreads();
    }

    // epilogue: C/D layout col=lane&15, row=(lane>>4)*4+reg
#pragma unroll
    for (int mf = 0; mf < 4; ++mf) {
#pragma unroll
        for (int nf = 0; nf < 4; ++nf) {
            const int nn = n0 + wn * 64 + nf * 16 + c;
            const int rb = r0 + wm * 64 + mf * 16 + g * 4;
            if constexpr (EPI == 0) {
                const int s = nn >> 9, rem = nn & 511;
                const int hh = rem >> 6, dd = rem & 63;
                const int bb = rb >> 11, t0 = rb & 2047;
                float v[4];
#pragma unroll
                for (int r = 0; r < 4; ++r) v[r] = acc[mf][nf][r] + bias[nn];
                if (s == 2) {
                    // V section: write transposed  vT[bh][d][T]
                    ushort4 u;
                    u.x = f2b(v[0]); u.y = f2b(v[1]); u.z = f2b(v[2]); u.w = f2b(v[3]);
                    *(ushort4*)((u16*)out + (size_t)2 * KQV_SEC +
                                (((size_t)(bb * H_ + hh) * D_ + dd) * T_ + t0)) = u;
                } else {
#pragma unroll
                    for (int r = 0; r < 4; ++r)
                        ((u16*)out)[(size_t)s * KQV_SEC +
                                    (((size_t)(bb * H_ + hh) * T_ + t0 + r) * D_ + dd)] = f2b(v[r]);
                }
            } else {
#pragma unroll
                for (int r = 0; r < 4; ++r) {
                    const int rr = rb + r;
                    float v = acc[mf][nf][r];
                    if constexpr (EPI != 3) v += bias[nn];
                    if constexpr (EPI == 1) {
                        v += resid[(size_t)rr * N + nn];
                        ((float*)out)[(size_t)rr * N + nn] = v;
                    } else if constexpr (EPI == 2) {
                        float ge = 0.5f * v * (1.0f + erff(v * 0.70710678118654752f));
                        ((u16*)out)[(size_t)rr * N + nn] = f2b(ge);
                    } else {
                        v += resid[(size_t)rr * N + nn];
                        ((float*)out)[(size_t)rr * N + nn] = v;
                    }
                }
            }
        }
    }
}

// ---------------- split-KV swapped-operand 32x32 MFMA flash attention ----------------
// 512 threads = 8 waves: waves 0-3 keys [0,1024), waves 4-7 keys [1024,2048),
// same 128 q rows. Zero-LDS main loop (LDS only for final merge).
// 2-tile ping-pong pipeline: QK^T(t+1) MFMAs issue before softmax(t) VALU so the
// matrix and vector pipes overlap; K/V loads issued 1-1.5 phases ahead.
// exp2 domain: Q pre-scaled by 0.125*log2(e); all exps are exp2f (v_exp native).
__global__ __launch_bounds__(512) void attn_mfma4_k(const u16* __restrict__ Kb,
                                                    const u16* __restrict__ Qb,
                                                    const u16* __restrict__ VTb,
                                                    u16* __restrict__ agg) {
    __shared__ float mlS[4][2][64][2];   // 4 KB
    __shared__ float oS[4][64][34];      // 34 KB

    const int tid = threadIdx.x;
    const int lane = tid & 63;
    const int w = tid >> 6;        // 0..7
    const int qw = w & 3;          // q-chunk within block
    const int half = w >> 2;       // KV half
    const int q = lane & 31;
    const int hi = lane >> 5;

    // XCD swizzle: id%8 = head-group; each XCD caches 4 heads' K/V in its L2
    const int id = blockIdx.x;          // 0..511
    const int gg = id & 7, rr_ = id >> 3;
    const int qt = rr_ & 15;            // 0..15
    const int bh = gg * 4 + (rr_ >> 4); // 0..31
    const int b = bh >> 3, h = bh & 7;
    const int q0 = qt * 128 + qw * 32;

    const u16* Kbh = Kb + (size_t)bh * T_ * D_;
    const u16* Qbh = Qb + (size_t)bh * T_ * D_;
    const u16* VTbh = VTb + (size_t)bh * D_ * T_;

    // Q B-fragments, pre-scaled by 0.125*log2(e) (exp2 domain)
    bf16x8 qf[4];
#pragma unroll
    for (int ks = 0; ks < 4; ++ks) {
        bf16x8 v = *(const bf16x8*)(Qbh + (size_t)(q0 + q) * D_ + ks * 16 + hi * 8);
#pragma unroll
        for (int i = 0; i < 8; ++i)
            ((u16*)&qf[ks])[i] = f2b(b2f(((const u16*)&v)[i]) * 0.18033688011f);
    }

    f32x16 accO0 = {}, accO1 = {};
    float m_r = -1e30f, l_r = 0.f;
    const int jbase = half * 1024;

    auto LK = [&](int j0, bf16x8* k0, bf16x8* k1) {
#pragma unroll
        for (int ks = 0; ks < 4; ++ks) {
            k0[ks] = *(const bf16x8*)(Kbh + (size_t)(j0 + q) * D_ + ks * 16 + hi * 8);
            k1[ks] = *(const bf16x8*)(Kbh + (size_t)(j0 + 32 + q) * D_ + ks * 16 + hi * 8);
        }
    };
    auto LV = [&](int j0, bf16x8* v0, bf16x8* v1) {
#pragma unroll
        for (int ks = 0; ks < 4; ++ks) {
            v0[ks] = *(const bf16x8*)(VTbh + (size_t)q * T_ + j0 + ks * 16 + hi * 8);
            v1[ks] = *(const bf16x8*)(VTbh + (size_t)(32 + q) * T_ + j0 + ks * 16 + hi * 8);
        }
    };
    auto QKT = [&](const bf16x8* k0, const bf16x8* k1, f32x16& s0, f32x16& s1) {
        f32x16 a = {}, c = {};
        __builtin_amdgcn_s_setprio(1);
#pragma unroll
        for (int ks = 0; ks < 4; ++ks) {
            a = __builtin_amdgcn_mfma_f32_32x32x16_bf16(k0[ks], qf[ks], a, 0, 0, 0);
            c = __builtin_amdgcn_mfma_f32_32x32x16_bf16(k1[ks], qf[ks], c, 0, 0, 0);
        }
        __builtin_amdgcn_s_setprio(0);
        s0 = a; s1 = c;
    };
    auto SMPV = [&](f32x16& s0, f32x16& s1, const bf16x8* v0, const bf16x8* v1) {
        // tree max + cross-half permlane swap
        float t8[8];
#pragma unroll
        for (int r = 0; r < 8; ++r)
            t8[r] = fmaxf(fmaxf(s0[r], s0[r + 8]), fmaxf(s1[r], s1[r + 8]));
        float pm = fmaxf(fmaxf(fmaxf(t8[0], t8[1]), fmaxf(t8[2], t8[3])),
                         fmaxf(fmaxf(t8[4], t8[5]), fmaxf(t8[6], t8[7])));
        {
            float a = pm, bs = pm;
            asm("v_permlane32_swap_b32 %0, %1" : "+v"(a), "+v"(bs));
            pm = fmaxf(a, bs);
        }
        // deferred-max rescale (log2 units; p bounded by 2^8)
        if (pm > m_r + 8.0f) {
            const float corr = exp2f(m_r - pm);
            l_r *= corr;
#pragma unroll
            for (int r = 0; r < 16; ++r) { accO0[r] *= corr; accO1[r] *= corr; }
            m_r = pm;
        }
        // p = exp2(s - m), pack to bf16 pairs, tree row-sum
        unsigned pk0[8], pk1[8];
        float sums[8];
#pragma unroll
        for (int j = 0; j < 8; ++j) {
            float a0 = exp2f(s0[2 * j] - m_r);
            float a1 = exp2f(s0[2 * j + 1] - m_r);
            float c0 = exp2f(s1[2 * j] - m_r);
            float c1 = exp2f(s1[2 * j + 1] - m_r);
            sums[j] = (a0 + a1) + (c0 + c1);
            asm("v_cvt_pk_bf16_f32 %0, %1, %2" : "=v"(pk0[j]) : "v"(a0), "v"(a1));
            asm("v_cvt_pk_bf16_f32 %0, %1, %2" : "=v"(pk1[j]) : "v"(c0), "v"(c1));
        }
        l_r += ((sums[0] + sums[1]) + (sums[2] + sums[3])) +
               ((sums[4] + sums[5]) + (sums[6] + sums[7]));
        // P^T fragments via permlane32_swap + PV
        __builtin_amdgcn_s_setprio(1);
#pragma unroll
        for (int ks = 0; ks < 4; ++ks) {
            const int s4 = (ks & 1) * 4;
            unsigned a0, a1, b0, b1;
            if (ks < 2) { a0 = pk0[s4]; a1 = pk0[s4 + 1]; b0 = pk0[s4 + 2]; b1 = pk0[s4 + 3]; }
            else        { a0 = pk1[s4]; a1 = pk1[s4 + 1]; b0 = pk1[s4 + 2]; b1 = pk1[s4 + 3]; }
            asm("v_permlane32_swap_b32 %0, %1" : "+v"(a0), "+v"(b0));
            asm("v_permlane32_swap_b32 %0, %1" : "+v"(a1), "+v"(b1));
            unsigned fw[4] = {a0, a1, b0, b1};
            bf16x8 pfr = *(bf16x8*)fw;
            accO0 = __builtin_amdgcn_mfma_f32_32x32x16_bf16(v0[ks], pfr, accO0, 0, 0, 0);
            accO1 = __builtin_amdgcn_mfma_f32_32x32x16_bf16(v1[ks], pfr, accO1, 0, 0, 0);
        }
        __builtin_amdgcn_s_setprio(0);
    };

    // ---- 2-tile ping-pong pipeline over 16 tiles ----
    bf16x8 kA0[4], kA1[4], kB0[4], kB1[4];
    bf16x8 vA0[4], vA1[4], vB0[4], vB1[4];
    f32x16 sA0, sA1, sB0, sB1;

    LK(jbase, kA0, kA1);
    LV(jbase, vA0, vA1);
    QKT(kA0, kA1, sA0, sA1);
    LK(jbase + 64, kB0, kB1);
    LV(jbase + 64, vB0, vB1);

    for (int t = 0; t < 16; t += 2) {
        QKT(kB0, kB1, sB0, sB1);                       // tile t+1 scores (MFMA pipe)
        if (t + 2 < 16) LK(jbase + (t + 2) * 64, kA0, kA1);
        SMPV(sA0, sA1, vA0, vA1);                      // tile t softmax+PV (VALU+MFMA)
        if (t + 2 < 16) {
            LV(jbase + (t + 2) * 64, vA0, vA1);        // vA freed by SMPV above
            QKT(kA0, kA1, sA0, sA1);                   // tile t+2 scores
        }
        if (t + 3 < 16) LK(jbase + (t + 3) * 64, kB0, kB1);
        SMPV(sB0, sB1, vB0, vB1);                      // tile t+1 softmax+PV
        if (t + 3 < 16) LV(jbase + (t + 3) * 64, vB0, vB1);
    }

    // ---- cross-hi l sum ----
    {
        float a = l_r, bs = l_r;
        asm("v_permlane32_swap_b32 %0, %1" : "+v"(a), "+v"(bs));
        l_r = a + bs;
    }

    // ---- merge the two KV halves through LDS ----
    mlS[qw][half][lane][0] = m_r;
    mlS[qw][half][lane][1] = l_r;
    __syncthreads();
    const float pm2 = mlS[qw][1 - half][lane][0];
    const float pl2 = mlS[qw][1 - half][lane][1];
    const float M = fmaxf(m_r, pm2);
    const float f_own = exp2f(m_r - M);
    const float l_comb = f_own * l_r + exp2f(pm2 - M) * pl2;
    if (half == 1) {
        float* oP = &oS[qw][lane][0];
#pragma unroll
        for (int r = 0; r < 16; ++r) oP[r] = accO0[r] * f_own;
#pragma unroll
        for (int r = 0; r < 16; ++r) oP[16 + r] = accO1[r] * f_own;
    }
    __syncthreads();
    if (half == 0) {
        const float inv = 1.0f / l_comb;
        const float* oP = &oS[qw][lane][0];
        u16* outp = agg + ((size_t)b * T_ + q0 + q) * C_ + h * D_;
#pragma unroll
        for (int r2 = 0; r2 < 8; ++r2) {
            const int r = 2 * r2;
            const int d = (r & 3) + 8 * (r >> 2) + 4 * hi;
            ushort2 o0, o1;
            o0.x = f2b((accO0[r] * f_own + oP[r]) * inv);
            o0.y = f2b((accO0[r + 1] * f_own + oP[r + 1]) * inv);
            o1.x = f2b((accO1[r] * f_own + oP[16 + r]) * inv);
            o1.y = f2b((accO1[r + 1] * f_own + oP[16 + r + 1]) * inv);
            *(ushort2*)(outp + d) = o0;
            *(ushort2*)(outp + 32 + d) = o1;
        }
    }
}

// ---------------- launch ----------------
extern "C" void kernel_launch(void* const* d_in, const int* in_sizes, int n_in,
                              void* d_out, int out_size, void* d_ws, size_t ws_size,
                              hipStream_t stream) {
    (void)in_sizes; (void)n_in; (void)out_size; (void)ws_size;
    const float* x       = (const float*)d_in[0];
    const float* w_kqv   = (const float*)d_in[1];
    const float* b_kqv   = (const float*)d_in[2];
    const float* w_proj  = (const float*)d_in[3];
    const float* b_proj  = (const float*)d_in[4];
    const float* w_fc    = (const float*)d_in[5];
    const float* b_fc    = (const float*)d_in[6];
    const float* w_cproj = (const float*)d_in[7];

    char* ws = (char*)d_ws;
    u16* wq_b = (u16*)(ws + 0);                    // 1.5 MB
    u16* wp_b = (u16*)(ws + (1536 * 512) * 2);     // 0.5 MB
    u16* wf_b = (u16*)(ws + (1536 * 512 + 512 * 512) * 2);              // 1 MB
    u16* wc_b = (u16*)(ws + (1536 * 512 + 512 * 512 + 1024 * 512) * 2); // 1 MB
    u16* lnbuf = (u16*)(ws + (4ull << 20));        // 8 MB (ln1 then ln2 output)
    u16* kqv  = (u16*)(ws + (12ull << 20));        // 24 MB (K,Q sections + vT)
    u16* hbuf = (u16*)(ws + (12ull << 20));        // overlays kqv (dead after attn)
    u16* agg  = (u16*)(ws + (36ull << 20));        // 8 MB
    float* x2 = (float*)(ws + (44ull << 20));      // 16 MB

    // all weights -> bf16 (one launch)
    wcvt_all_k<<<524288 / 256, 256, 0, stream>>>(
        w_kqv, w_proj, w_fc, w_cproj, wq_b, wp_b, wf_b, wc_b);

    // ln1 -> bf16
    ln_fused_k<<<BT, 256, 0, stream>>>(x, lnbuf);
    // kqv = ln1(x) @ w_kqv^T + b_kqv  -> K,Q scattered [bh][T][64]; V transposed [bh][64][T]
    gemm_mfma<0><<<dim3(1536 / 128, BT / 128), 256, 0, stream>>>(
        lnbuf, wq_b, b_kqv, nullptr, kqv, 512, 1536);
    // attention (split-KV, 8 waves, XCD-swizzled, 2-tile ping-pong)
    attn_mfma4_k<<<512, 512, 0, stream>>>(
        kqv, kqv + KQV_SEC, kqv + 2 * KQV_SEC, agg);
    // x2 = x + agg @ w_proj^T + b_proj   (f32)
    gemm_mfma<1><<<dim3(512 / 128, BT / 128), 256, 0, stream>>>(
        agg, wp_b, b_proj, x, x2, 512, 512);
    // ln2 -> bf16
    ln_fused_k<<<BT, 256, 0, stream>>>(x2, lnbuf);
    // h = gelu(ln2(x2) @ w_fc^T + b_fc)  (bf16)
    gemm_mfma<2><<<dim3(1024 / 128, BT / 128), 256, 0, stream>>>(
        lnbuf, wf_b, b_fc, nullptr, hbuf, 512, 1024);
    // out = x2 + h @ w_cproj^T           (f32)
    gemm_mfma<3><<<dim3(512 / 128, BT / 128), 256, 0, stream>>>(
        hbuf, wc_b, nullptr, x2, d_out, 1024, 512);
}

// Round 11
// 181.132 us; speedup vs baseline: 1.7226x; 1.7226x over previous
//
#include <hip/hip_runtime.h>
#include <hip/hip_bf16.h>
#include <cmath>

// TransformerBlock  B=4 T=2048 C=512 H=8 D=64  (f32 I/O, bf16 MFMA internal)

using u16 = unsigned short;
typedef __attribute__((ext_vector_type(4))) float f32x4;
typedef __attribute__((ext_vector_type(16))) float f32x16;
typedef __attribute__((ext_vector_type(8))) short bf16x8;

constexpr int B_ = 4, T_ = 2048, C_ = 512, H_ = 8, D_ = 64;
constexpr int BT = B_ * T_;                // 8192 rows
constexpr int KQV_SEC = B_ * H_ * T_ * D_; // 4194304 elems per k/q/v section

__device__ __forceinline__ float b2f(u16 u) {
    return __uint_as_float(((unsigned)u) << 16);
}
__device__ __forceinline__ u16 f2b(float f) {
    __hip_bfloat16 h = __float2bfloat16(f);
    return *reinterpret_cast<u16*>(&h);
}

// async global->LDS, 16B per lane; LDS dest = wave-uniform base + lane*16
__device__ __forceinline__ void gl_lds16(const u16* g, u16* l) {
    __builtin_amdgcn_global_load_lds(
        (const __attribute__((address_space(1))) unsigned int*)(const void*)g,
        (__attribute__((address_space(3))) unsigned int*)(void*)l, 16, 0, 0);
}

// ---------------- all weights f32 -> bf16, one launch ----------------
__global__ __launch_bounds__(256) void wcvt_all_k(const float* __restrict__ w0,
                                                  const float* __restrict__ w1,
                                                  const float* __restrict__ w2,
                                                  const float* __restrict__ w3,
                                                  u16* __restrict__ o0,
                                                  u16* __restrict__ o1,
                                                  u16* __restrict__ o2,
                                                  u16* __restrict__ o3) {
    const int i = blockIdx.x * 256 + threadIdx.x;
    const float* w; u16* o; int j;
    if (i < 196608) { w = w0; o = o0; j = i; }
    else if (i < 262144) { w = w1; o = o1; j = i - 196608; }
    else if (i < 393216) { w = w2; o = o2; j = i - 262144; }
    else { w = w3; o = o3; j = i - 393216; }
    float4 v = ((const float4*)w)[j];
    ushort4 u;
    u.x = f2b(v.x); u.y = f2b(v.y); u.z = f2b(v.z); u.w = f2b(v.w);
    ((ushort4*)o)[j] = u;
}

// ---------------- fused LayerNorm: f32 in -> bf16 normalized out ----------------
__global__ __launch_bounds__(256) void ln_fused_k(const float* __restrict__ x,
                                                  u16* __restrict__ o) {
    const int r = blockIdx.x;
    const int t = threadIdx.x;
    const float v0 = x[(size_t)r * C_ + t];
    const float v1 = x[(size_t)r * C_ + t + 256];
    __shared__ float rs[256], rq[256];
    rs[t] = v0 + v1;
    rq[t] = v0 * v0 + v1 * v1;
    __syncthreads();
    for (int k = 128; k; k >>= 1) {
        if (t < k) { rs[t] += rs[t + k]; rq[t] += rq[t + k]; }
        __syncthreads();
    }
    __shared__ float sm, sr;
    if (t == 0) {
        float m = rs[0] * (1.0f / C_);
        float var = rq[0] * (1.0f / C_) - m * m;
        sm = m;
        sr = rsqrtf(var + 1e-5f);
    }
    __syncthreads();
    const float m = sm, rstd = sr;
    o[(size_t)r * C_ + t] = f2b((v0 - m) * rstd);
    o[(size_t)r * C_ + t + 256] = f2b((v1 - m) * rstd);
}

// ---------------- MFMA GEMM: out = A(bf16 [M][K]) @ W(bf16 [N][K])^T ----------------
// 128x128 tile, BK=64, 4 waves each 64x64. global_load_lds staging with
// inverse-swizzled global source (rule #21).
// EPI: 0 kqv scatter (+bias, bf16; V section written TRANSPOSED [bh][d][T])
//      1 +bias+resid(f32)->f32 | 2 +bias,gelu->bf16 | 3 +resid->f32
template <int EPI>
__global__ __launch_bounds__(256) void gemm_mfma(const u16* __restrict__ A,
                                                 const u16* __restrict__ W,
                                                 const float* __restrict__ bias,
                                                 const float* __restrict__ resid,
                                                 void* __restrict__ out,
                                                 int K, int N) {
    __shared__ alignas(16) u16 Al[128 * 64];
    __shared__ alignas(16) u16 Bl[128 * 64];
    const int tid = threadIdx.x, lane = tid & 63, w = tid >> 6;
    const int g = lane >> 4, c = lane & 15;
    const int wm = w >> 1, wn = w & 1;
    const int n0 = blockIdx.x * 128, r0 = blockIdx.y * 128;

    const int l7 = lane & 7, l3 = lane >> 3;
    const int colHalf = ((l7 ^ l3) << 3);   // swizzled source column (elements)

    f32x4 acc[4][4] = {};
    const char* AlB = (const char*)Al;
    const char* BlB = (const char*)Bl;

    for (int kk = 0; kk < K; kk += 64) {
#pragma unroll
        for (int i = 0; i < 4; ++i) {
            const int s = w * 4 + i;
            const int row = s * 8 + l3;
            gl_lds16(A + (size_t)(r0 + row) * K + kk + colHalf, &Al[s * 512]);
            gl_lds16(W + (size_t)(n0 + row) * K + kk + colHalf, &Bl[s * 512]);
        }
        __syncthreads();

        bf16x8 af[4][2], bf[4][2];
#pragma unroll
        for (int mf = 0; mf < 4; ++mf) {
            const int ar = wm * 64 + mf * 16 + c;
#pragma unroll
            for (int ch = 0; ch < 2; ++ch)
                af[mf][ch] = *(const bf16x8*)(
                    AlB + ar * 128 + (((ch * 32 + g * 8) * 2) ^ ((ar & 7) << 4)));
        }
#pragma unroll
        for (int nf = 0; nf < 4; ++nf) {
            const int br = wn * 64 + nf * 16 + c;
#pragma unroll
            for (int ch = 0; ch < 2; ++ch)
                bf[nf][ch] = *(const bf16x8*)(
                    BlB + br * 128 + (((ch * 32 + g * 8) * 2) ^ ((br & 7) << 4)));
        }
#pragma unroll
        for (int mf = 0; mf < 4; ++mf)
#pragma unroll
            for (int nf = 0; nf < 4; ++nf)
#pragma unroll
                for (int ch = 0; ch < 2; ++ch)
                    acc[mf][nf] = __builtin_amdgcn_mfma_f32_16x16x32_bf16(
                        af[mf][ch], bf[nf][ch], acc[mf][nf], 0, 0, 0);
        __syncthreads();
    }

    // epilogue: C/D layout col=lane&15, row=(lane>>4)*4+reg
#pragma unroll
    for (int mf = 0; mf < 4; ++mf) {
#pragma unroll
        for (int nf = 0; nf < 4; ++nf) {
            const int nn = n0 + wn * 64 + nf * 16 + c;
            const int rb = r0 + wm * 64 + mf * 16 + g * 4;
            if constexpr (EPI == 0) {
                const int s = nn >> 9, rem = nn & 511;
                const int hh = rem >> 6, dd = rem & 63;
                const int bb = rb >> 11, t0 = rb & 2047;
                float v[4];
#pragma unroll
                for (int r = 0; r < 4; ++r) v[r] = acc[mf][nf][r] + bias[nn];
                if (s == 2) {
                    // V section: write transposed  vT[bh][d][T]
                    ushort4 u;
                    u.x = f2b(v[0]); u.y = f2b(v[1]); u.z = f2b(v[2]); u.w = f2b(v[3]);
                    *(ushort4*)((u16*)out + (size_t)2 * KQV_SEC +
                                (((size_t)(bb * H_ + hh) * D_ + dd) * T_ + t0)) = u;
                } else {
#pragma unroll
                    for (int r = 0; r < 4; ++r)
                        ((u16*)out)[(size_t)s * KQV_SEC +
                                    (((size_t)(bb * H_ + hh) * T_ + t0 + r) * D_ + dd)] = f2b(v[r]);
                }
            } else {
#pragma unroll
                for (int r = 0; r < 4; ++r) {
                    const int rr = rb + r;
                    float v = acc[mf][nf][r];
                    if constexpr (EPI != 3) v += bias[nn];
                    if constexpr (EPI == 1) {
                        v += resid[(size_t)rr * N + nn];
                        ((float*)out)[(size_t)rr * N + nn] = v;
                    } else if constexpr (EPI == 2) {
                        float ge = 0.5f * v * (1.0f + erff(v * 0.70710678118654752f));
                        ((u16*)out)[(size_t)rr * N + nn] = f2b(ge);
                    } else {
                        v += resid[(size_t)rr * N + nn];
                        ((float*)out)[(size_t)rr * N + nn] = v;
                    }
                }
            }
        }
    }
}

// ---------------- LDS-staged swapped-operand 32x32 MFMA flash attention ----------------
// 4 waves x 32 q-rows. K and Vt tiles staged ONCE per block via global_load_lds
// (coalesced, inverse-swizzled source), double-buffered by tile parity.
// Per tile: QK^T(t+1) MFMAs issue before softmax(t) VALU (pipe overlap).
// K staged early (K-buf dead after its QKT); V staged after the barrier that
// retires its readers. One barrier per tile. exp2 domain softmax.
__global__ __launch_bounds__(256, 2) void attn_mfma5_k(const u16* __restrict__ Kb,
                                                       const u16* __restrict__ Qb,
                                                       const u16* __restrict__ VTb,
                                                       u16* __restrict__ agg) {
    __shared__ alignas(16) u16 Kl[2][64 * 64];
    __shared__ alignas(16) u16 Vl[2][64 * 64];

    const int tid = threadIdx.x;
    const int lane = tid & 63;
    const int w = tid >> 6;        // 0..3
    const int q = lane & 31;
    const int hi = lane >> 5;
    const int l7 = lane & 7, l3 = lane >> 3;
    const int colHalf = ((l7 ^ l3) << 3);   // inverse-swizzled source column (elems)

    // XCD swizzle: id%8 = head-group; each XCD caches 4 heads' K/V in its L2
    const int id = blockIdx.x;          // 0..511
    const int gg = id & 7, rr_ = id >> 3;
    const int qt = rr_ & 15;            // 0..15
    const int bh = gg * 4 + (rr_ >> 4); // 0..31
    const int b = bh >> 3, h = bh & 7;
    const int q0 = qt * 128 + w * 32;

    const u16* Kbh = Kb + (size_t)bh * T_ * D_;
    const u16* Qbh = Qb + (size_t)bh * T_ * D_;
    const u16* VTbh = VTb + (size_t)bh * D_ * T_;

    // Q B-fragments, pre-scaled by 0.125*log2(e) (exp2 domain)
    bf16x8 qf[4];
#pragma unroll
    for (int ks = 0; ks < 4; ++ks) {
        bf16x8 v = *(const bf16x8*)(Qbh + (size_t)(q0 + q) * D_ + ks * 16 + hi * 8);
#pragma unroll
        for (int i = 0; i < 8; ++i)
            ((u16*)&qf[ks])[i] = f2b(b2f(((const u16*)&v)[i]) * 0.18033688011f);
    }

    f32x16 accO0 = {}, accO1 = {};
    float m_r = -1e30f, l_r = 0.f;

    // ---- staging: wave w covers segments w*2, w*2+1 (8 rows = 1 KB each) ----
    auto stageK = [&](int buf, int tt) {
#pragma unroll
        for (int i = 0; i < 2; ++i) {
            const int s = w * 2 + i;
            const int row = s * 8 + l3;
            gl_lds16(Kbh + (size_t)(tt * 64 + row) * D_ + colHalf, &Kl[buf][s * 512]);
        }
    };
    auto stageV = [&](int buf, int tt) {
#pragma unroll
        for (int i = 0; i < 2; ++i) {
            const int s = w * 2 + i;
            const int row = s * 8 + l3;   // d index
            gl_lds16(VTbh + (size_t)row * T_ + tt * 64 + colHalf, &Vl[buf][s * 512]);
        }
    };

    auto QKT = [&](int buf, f32x16& s0, f32x16& s1) {
        const char* KB = (const char*)Kl[buf];
        f32x16 a = {}, c = {};
        __builtin_amdgcn_s_setprio(1);
#pragma unroll
        for (int ks = 0; ks < 4; ++ks) {
            bf16x8 k0 = *(const bf16x8*)(KB + q * 128 + ((ks * 32 + hi * 16) ^ ((q & 7) << 4)));
            bf16x8 k1 = *(const bf16x8*)(KB + (32 + q) * 128 + ((ks * 32 + hi * 16) ^ ((q & 7) << 4)));
            a = __builtin_amdgcn_mfma_f32_32x32x16_bf16(k0, qf[ks], a, 0, 0, 0);
            c = __builtin_amdgcn_mfma_f32_32x32x16_bf16(k1, qf[ks], c, 0, 0, 0);
        }
        __builtin_amdgcn_s_setprio(0);
        s0 = a; s1 = c;
    };

    auto SMPV = [&](f32x16& s0, f32x16& s1, int buf) {
        const char* VB = (const char*)Vl[buf];
        // tree max + cross-half permlane swap
        float t8[8];
#pragma unroll
        for (int r = 0; r < 8; ++r)
            t8[r] = fmaxf(fmaxf(s0[r], s0[r + 8]), fmaxf(s1[r], s1[r + 8]));
        float pm = fmaxf(fmaxf(fmaxf(t8[0], t8[1]), fmaxf(t8[2], t8[3])),
                         fmaxf(fmaxf(t8[4], t8[5]), fmaxf(t8[6], t8[7])));
        {
            float a = pm, bs = pm;
            asm("v_permlane32_swap_b32 %0, %1" : "+v"(a), "+v"(bs));
            pm = fmaxf(a, bs);
        }
        // deferred-max rescale (log2 units; p bounded by 2^8)
        if (pm > m_r + 8.0f) {
            const float corr = exp2f(m_r - pm);
            l_r *= corr;
#pragma unroll
            for (int r = 0; r < 16; ++r) { accO0[r] *= corr; accO1[r] *= corr; }
            m_r = pm;
        }
        // p = exp2(s - m), pack to bf16 pairs, tree row-sum
        unsigned pk0[8], pk1[8];
        float sums[8];
#pragma unroll
        for (int j = 0; j < 8; ++j) {
            float a0 = exp2f(s0[2 * j] - m_r);
            float a1 = exp2f(s0[2 * j + 1] - m_r);
            float c0 = exp2f(s1[2 * j] - m_r);
            float c1 = exp2f(s1[2 * j + 1] - m_r);
            sums[j] = (a0 + a1) + (c0 + c1);
            asm("v_cvt_pk_bf16_f32 %0, %1, %2" : "=v"(pk0[j]) : "v"(a0), "v"(a1));
            asm("v_cvt_pk_bf16_f32 %0, %1, %2" : "=v"(pk1[j]) : "v"(c0), "v"(c1));
        }
        l_r += ((sums[0] + sums[1]) + (sums[2] + sums[3])) +
               ((sums[4] + sums[5]) + (sums[6] + sums[7]));
        // P^T fragments via permlane32_swap + PV (V frags from LDS)
        __builtin_amdgcn_s_setprio(1);
#pragma unroll
        for (int ks = 0; ks < 4; ++ks) {
            const int s4 = (ks & 1) * 4;
            unsigned a0, a1, b0, b1;
            if (ks < 2) { a0 = pk0[s4]; a1 = pk0[s4 + 1]; b0 = pk0[s4 + 2]; b1 = pk0[s4 + 3]; }
            else        { a0 = pk1[s4]; a1 = pk1[s4 + 1]; b0 = pk1[s4 + 2]; b1 = pk1[s4 + 3]; }
            asm("v_permlane32_swap_b32 %0, %1" : "+v"(a0), "+v"(b0));
            asm("v_permlane32_swap_b32 %0, %1" : "+v"(a1), "+v"(b1));
            unsigned fw[4] = {a0, a1, b0, b1};
            bf16x8 pfr = *(bf16x8*)fw;
            bf16x8 v0 = *(const bf16x8*)(VB + q * 128 + ((ks * 32 + hi * 16) ^ ((q & 7) << 4)));
            bf16x8 v1 = *(const bf16x8*)(VB + (32 + q) * 128 + ((ks * 32 + hi * 16) ^ ((q & 7) << 4)));
            accO0 = __builtin_amdgcn_mfma_f32_32x32x16_bf16(v0, pfr, accO0, 0, 0, 0);
            accO1 = __builtin_amdgcn_mfma_f32_32x32x16_bf16(v1, pfr, accO1, 0, 0, 0);
        }
        __builtin_amdgcn_s_setprio(0);
    };

    // ---- prologue: tile 0 fully staged; tile 1 staged behind it ----
    stageK(0, 0);
    stageV(0, 0);
    __syncthreads();                 // tile 0 ready
    stageK(1, 1);
    f32x16 sA0, sA1, sB0, sB1;
    QKT(0, sA0, sA1);                // S(0)
    stageV(1, 1);
    __syncthreads();                 // tile 1 (K+V) ready

    // ---- main loop: 2 tiles per iteration, fixed buffer parity (tile j -> buf j&1)
    for (int t = 0; t < 32; t += 2) {
        // phase A: consume tile t (buf0); S(t) in sA
        if (t + 2 < 32) stageK(0, t + 2);          // K(t) dead -> stage K(t+2)
        if (t + 1 < 32) QKT(1, sB0, sB1);          // S(t+1), overlaps SMPV VALU below
        SMPV(sA0, sA1, 0);                         // softmax+PV tile t
        __syncthreads();                           // retires V(t) readers; drains K(t+2)
        if (t + 2 < 32) stageV(0, t + 2);
        // phase B: consume tile t+1 (buf1); S(t+1) in sB
        if (t + 3 < 32) stageK(1, t + 3);
        if (t + 2 < 32) QKT(0, sA0, sA1);          // S(t+2) (K staged in phase A)
        SMPV(sB0, sB1, 1);
        __syncthreads();                           // retires V(t+1); drains V(t+2),K(t+3)
        if (t + 3 < 32) stageV(1, t + 3);
    }

    // ---- cross-hi l sum, normalize, write agg[b][t][h*64+d] ----
    {
        float a = l_r, bs = l_r;
        asm("v_permlane32_swap_b32 %0, %1" : "+v"(a), "+v"(bs));
        l_r = a + bs;
    }
    const float inv = 1.0f / l_r;
    u16* outp = agg + ((size_t)b * T_ + q0 + q) * C_ + h * D_;
#pragma unroll
    for (int r2 = 0; r2 < 8; ++r2) {
        const int r = 2 * r2;
        const int d = (r & 3) + 8 * (r >> 2) + 4 * hi;
        ushort2 o0, o1;
        o0.x = f2b(accO0[r] * inv);
        o0.y = f2b(accO0[r + 1] * inv);
        o1.x = f2b(accO1[r] * inv);
        o1.y = f2b(accO1[r + 1] * inv);
        *(ushort2*)(outp + d) = o0;
        *(ushort2*)(outp + 32 + d) = o1;
    }
}

// ---------------- launch ----------------
extern "C" void kernel_launch(void* const* d_in, const int* in_sizes, int n_in,
                              void* d_out, int out_size, void* d_ws, size_t ws_size,
                              hipStream_t stream) {
    (void)in_sizes; (void)n_in; (void)out_size; (void)ws_size;
    const float* x       = (const float*)d_in[0];
    const float* w_kqv   = (const float*)d_in[1];
    const float* b_kqv   = (const float*)d_in[2];
    const float* w_proj  = (const float*)d_in[3];
    const float* b_proj  = (const float*)d_in[4];
    const float* w_fc    = (const float*)d_in[5];
    const float* b_fc    = (const float*)d_in[6];
    const float* w_cproj = (const float*)d_in[7];

    char* ws = (char*)d_ws;
    u16* wq_b = (u16*)(ws + 0);                    // 1.5 MB
    u16* wp_b = (u16*)(ws + (1536 * 512) * 2);     // 0.5 MB
    u16* wf_b = (u16*)(ws + (1536 * 512 + 512 * 512) * 2);              // 1 MB
    u16* wc_b = (u16*)(ws + (1536 * 512 + 512 * 512 + 1024 * 512) * 2); // 1 MB
    u16* lnbuf = (u16*)(ws + (4ull << 20));        // 8 MB (ln1 then ln2 output)
    u16* kqv  = (u16*)(ws + (12ull << 20));        // 24 MB (K,Q sections + vT)
    u16* hbuf = (u16*)(ws + (12ull << 20));        // overlays kqv (dead after attn)
    u16* agg  = (u16*)(ws + (36ull << 20));        // 8 MB
    float* x2 = (float*)(ws + (44ull << 20));      // 16 MB

    // all weights -> bf16 (one launch)
    wcvt_all_k<<<524288 / 256, 256, 0, stream>>>(
        w_kqv, w_proj, w_fc, w_cproj, wq_b, wp_b, wf_b, wc_b);

    // ln1 -> bf16
    ln_fused_k<<<BT, 256, 0, stream>>>(x, lnbuf);
    // kqv = ln1(x) @ w_kqv^T + b_kqv  -> K,Q scattered [bh][T][64]; V transposed [bh][64][T]
    gemm_mfma<0><<<dim3(1536 / 128, BT / 128), 256, 0, stream>>>(
        lnbuf, wq_b, b_kqv, nullptr, kqv, 512, 1536);
    // attention (LDS-staged, 4 waves, XCD-swizzled, 2-tile pipeline)
    attn_mfma5_k<<<512, 256, 0, stream>>>(
        kqv, kqv + KQV_SEC, kqv + 2 * KQV_SEC, agg);
    // x2 = x + agg @ w_proj^T + b_proj   (f32)
    gemm_mfma<1><<<dim3(512 / 128, BT / 128), 256, 0, stream>>>(
        agg, wp_b, b_proj, x, x2, 512, 512);
    // ln2 -> bf16
    ln_fused_k<<<BT, 256, 0, stream>>>(x2, lnbuf);
    // h = gelu(ln2(x2) @ w_fc^T + b_fc)  (bf16)
    gemm_mfma<2><<<dim3(1024 / 128, BT / 128), 256, 0, stream>>>(
        lnbuf, wf_b, b_fc, nullptr, hbuf, 512, 1024);
    // out = x2 + h @ w_cproj^T           (f32)
    gemm_mfma<3><<<dim3(512 / 128, BT / 128), 256, 0, stream>>>(
        hbuf, wc_b, nullptr, x2, d_out, 1024, 512);
}